// Round 6
// baseline (2285.805 us; speedup 1.0000x reference)
//
#include <hip/hip_runtime.h>
#include <math.h>

#define NN 2048
#define NB 4
#define ROWS (NB*NN)   // 8192

// u' = u * S, v' = v * S, with S = log2(e)/eps. Then
// exp((-C+u+v)/eps) = exp2(-S*C + u' + v'), and
// u'_new = log2(mu+1e-8) - log2(sum_exp + 1e-6) + u'.
constexpr float SF      = 14.426950408889634f;   // log2(e)/0.1
constexpr float TWO_SF  = 28.853900817779268f;
constexpr float LOG2MU  = -10.99997045f;         // log2(1/2048 + 1e-8)
constexpr float ERRTHR  = 5.770780163555854f;    // 0.1 * B * S  (err in u'-units)

// done_iter: iteration index at which convergence was detected (1000 = never).
// Kernels of iteration i skip iff done_iter < i (STRICT) — an intra-kernel
// read of the just-written stamp (== i) does not skip, so the write by block 0
// of v-pass i racing with entry-reads of other blocks of v-pass i is harmless.
// Inter-kernel visibility is guaranteed by dispatch-boundary coherence.
struct Ctrl { int done_iter; };

// ws layout (bytes):
//   YQ4      [8192 float4]  @ 0        (2S*y0,2S*y1,2S*y2, v' - S*|y|^2)
//   XP4      [8192 float4]  @ 131072   (2S*x0,2S*x1,2S*x2, u' - S*|x|^2)
//   uarr     [8192 f32]     @ 262144
//   varr     [8192 f32]     @ 294912
//   err_rows [8192 f32]     @ 327680
//   ctrl                    @ 360448
//   partials [1024 f32]     @ 360512

__global__ __launch_bounds__(256) void k_init(
    const float* __restrict__ x, const float* __restrict__ y,
    float4* __restrict__ XP4, float4* __restrict__ YQ4,
    float* __restrict__ uarr, float* __restrict__ varr, Ctrl* ctrl)
{
  int r = blockIdx.x * 256 + threadIdx.x;
  if (r < ROWS) {
    float x0 = x[3*r], x1 = x[3*r+1], x2 = x[3*r+2];
    float y0 = y[3*r], y1 = y[3*r+1], y2 = y[3*r+2];
    float nx = fmaf(x0, x0, fmaf(x1, x1, x2*x2));
    float ny = fmaf(y0, y0, fmaf(y1, y1, y2*y2));
    XP4[r] = make_float4(TWO_SF*x0, TWO_SF*x1, TWO_SF*x2, -SF*nx);
    YQ4[r] = make_float4(TWO_SF*y0, TWO_SF*y1, TWO_SF*y2, -SF*ny);
    uarr[r] = 0.f; varr[r] = 0.f;
  }
  if (blockIdx.x == 0 && threadIdx.x == 0) { ctrl->done_iter = 1000; }
}

// One Sinkhorn half-pass. Each wave owns 4 consecutive rows (same batch).
// rowxyz: raw coords of rows being updated; rowP4: their float4 table
// (.w = potential' - S*|coord|^2, updated here); inner4: other side's table
// (read-only); rowu: scaled potential being updated.
// WRITE_ERR=1 -> u-pass (writes err_rows). WRITE_ERR=0 -> v-pass (block 0
// additionally reduces err_rows and stamps ctrl->done_iter on convergence).
template <int WRITE_ERR>
__global__ __launch_bounds__(256) void k_pass(
    const float* __restrict__ rowxyz,
    float4* __restrict__ rowP4,
    const float4* __restrict__ inner4,
    float* __restrict__ rowu,
    float* __restrict__ err_rows,
    Ctrl* __restrict__ ctrl,
    int it)
{
  __shared__ float red[256];
  if (ctrl->done_iter < it) return;   // strict: stamp==it still executes

  int wave = (int)((blockIdx.x * blockDim.x + threadIdx.x) >> 6); // 0..2047
  int lane = threadIdx.x & 63;
  int r0 = wave * 4;                 // four consecutive rows, same batch
  int b  = r0 >> 11;

  const float* p = rowxyz + (size_t)r0 * 3;
  float a0[4], a1[4], a2[4], P[4], s[4];
  #pragma unroll
  for (int r = 0; r < 4; ++r) {
    a0[r] = p[3*r]; a1[r] = p[3*r+1]; a2[r] = p[3*r+2];
    P[r] = rowP4[r0 + r].w;
    s[r] = 0.f;
  }
  const float4* Yb = inner4 + (size_t)b * NN;

  #pragma unroll 4
  for (int j = lane; j < NN; j += 64) {
    float4 Y = Yb[j];
    #pragma unroll
    for (int r = 0; r < 4; ++r) {
      float t = fmaf(a0[r], Y.x, fmaf(a1[r], Y.y, fmaf(a2[r], Y.z, Y.w + P[r])));
      s[r] += __builtin_amdgcn_exp2f(t);
    }
  }
  #pragma unroll
  for (int off = 32; off; off >>= 1) {
    #pragma unroll
    for (int r = 0; r < 4; ++r) s[r] += __shfl_xor(s[r], off);
  }

  if (lane == 0) {
    #pragma unroll
    for (int r = 0; r < 4; ++r) {
      float uo = rowu[r0 + r];
      float un = LOG2MU - __log2f(s[r] + 1e-6f) + uo;
      rowu[r0 + r] = un;
      rowP4[r0 + r].w = un - SF * fmaf(a0[r], a0[r], fmaf(a1[r], a1[r], a2[r]*a2[r]));
      if (WRITE_ERR) err_rows[r0 + r] = fabsf(un - uo);
    }
  }

  if (!WRITE_ERR) {
    // convergence decision (err_rows complete from the preceding u-pass)
    __syncthreads();
    if (blockIdx.x == 0) {
      float acc = 0.f;
      for (int t = threadIdx.x; t < ROWS; t += 256) acc += err_rows[t];
      red[threadIdx.x] = acc;
      __syncthreads();
      for (int st = 128; st; st >>= 1) {
        if ((int)threadIdx.x < st) red[threadIdx.x] += red[threadIdx.x + st];
        __syncthreads();
      }
      if (threadIdx.x == 0 && red[0] < ERRTHR && ctrl->done_iter > it)
        ctrl->done_iter = it;
    }
  }
}

__global__ __launch_bounds__(256) void k_final(
    const float* __restrict__ x, const float* __restrict__ y,
    const float* __restrict__ uarr, const float* __restrict__ varr,
    float* __restrict__ out, float* __restrict__ partials)
{
  __shared__ float bred[4];
  int wave = (int)((blockIdx.x * blockDim.x + threadIdx.x) >> 6);
  int lane = threadIdx.x & 63;
  int r0 = wave * 2;
  int b  = r0 >> 11;

  float* pi_out = out + 1;
  float* C_out  = out + 1 + (size_t)ROWS * NN;

  const float* xr = x + (size_t)r0 * 3;
  float a0 = xr[0], a1 = xr[1], a2 = xr[2];
  float c0 = xr[3], c1 = xr[4], c2 = xr[5];
  float u0 = uarr[r0], u1 = uarr[r0 + 1];
  const float* yb = y + (size_t)b * NN * 3;
  const float* vb = varr + (size_t)b * NN;

  float acc = 0.f;
  #pragma unroll 4
  for (int j = lane; j < NN; j += 64) {
    float y0 = yb[3*j], y1 = yb[3*j+1], y2 = yb[3*j+2];
    float vj = vb[j];
    float d0 = a0 - y0, d1 = a1 - y1, d2 = a2 - y2;
    float C0 = fmaf(d0, d0, fmaf(d1, d1, d2*d2));
    float e0 = c0 - y0, e1 = c1 - y1, e2 = c2 - y2;
    float C1 = fmaf(e0, e0, fmaf(e1, e1, e2*e2));
    float pi0 = __builtin_amdgcn_exp2f(fmaf(-SF, C0, u0 + vj));
    float pi1 = __builtin_amdgcn_exp2f(fmaf(-SF, C1, u1 + vj));
    size_t i0 = (size_t)r0 * NN + j;
    size_t i1 = i0 + NN;
    pi_out[i0] = pi0; C_out[i0] = C0;
    pi_out[i1] = pi1; C_out[i1] = C1;
    acc = fmaf(pi0, C0, acc);
    acc = fmaf(pi1, C1, acc);
  }
  #pragma unroll
  for (int off = 32; off; off >>= 1) acc += __shfl_xor(acc, off);
  if (lane == 0) bred[threadIdx.x >> 6] = acc;
  __syncthreads();
  if (threadIdx.x == 0)
    partials[blockIdx.x] = bred[0] + bred[1] + bred[2] + bred[3];
}

__global__ __launch_bounds__(256) void k_write(
    const float* __restrict__ partials, float* __restrict__ out)
{
  __shared__ float red[4];
  float acc = 0.f;
  for (int i = threadIdx.x; i < 1024; i += 256) acc += partials[i];
  #pragma unroll
  for (int off = 32; off; off >>= 1) acc += __shfl_xor(acc, off);
  if ((threadIdx.x & 63) == 0) red[threadIdx.x >> 6] = acc;
  __syncthreads();
  if (threadIdx.x == 0) out[0] = (red[0] + red[1] + red[2] + red[3]) * 0.25f;
}

extern "C" void kernel_launch(void* const* d_in, const int* in_sizes, int n_in,
                              void* d_out, int out_size, void* d_ws, size_t ws_size,
                              hipStream_t stream) {
  (void)in_sizes; (void)n_in; (void)out_size; (void)ws_size;
  const float* x = (const float*)d_in[0];
  const float* y = (const float*)d_in[1];
  float* out = (float*)d_out;

  char* ws = (char*)d_ws;
  float4* YQ4  = (float4*)(ws + 0);
  float4* XP4  = (float4*)(ws + 131072);
  float* uarr  = (float*)(ws + 262144);
  float* varr  = (float*)(ws + 294912);
  float* err_r = (float*)(ws + 327680);
  Ctrl*  ctrl  = (Ctrl*)(ws + 360448);
  float* parts = (float*)(ws + 360512);

  k_init<<<32, 256, 0, stream>>>(x, y, XP4, YQ4, uarr, varr, ctrl);

  for (int it = 0; it < 100; ++it) {
    // u-pass: rows = x rows, inner = YQ4
    k_pass<1><<<512, 256, 0, stream>>>(x, XP4, YQ4, uarr, err_r, ctrl, it);
    // v-pass: rows = y rows, inner = XP4 (holds u_new); stamps done_iter
    k_pass<0><<<512, 256, 0, stream>>>(y, YQ4, XP4, varr, err_r, ctrl, it);
  }

  k_final<<<1024, 256, 0, stream>>>(x, y, uarr, varr, out, parts);
  k_write<<<1, 256, 0, stream>>>(parts, out);
}